// Round 4
// baseline (153.370 us; speedup 1.0000x reference)
//
#include <hip/hip_runtime.h>
#include <math.h>

#define CAP   32768
#define NB    32
#define ROWS  64
#define NBLK  (CAP / ROWS)   // 512
#define TOPK  16
#define CEPS  1e-8f

#define PITCH 68              // LDS row pitch (floats)
#define CHUNK 2048
#define NCHUNK (CAP / CHUNK)  // 16

// ws layout: final scores [32][32768] at offset 0
#define WS_FINAL 0

__global__ __launch_bounds__(256) void score_kernel(
    const float* __restrict__ qc,     // [32][64]
    const float* __restrict__ qctx,   // [32][64]
    const float* __restrict__ mcont,  // [CAP][64]
    const float* __restrict__ mctx,   // [CAP][64]
    const float* __restrict__ fresh,  // [CAP]
    const float* __restrict__ W1,     // [128][64]
    const float* __restrict__ b1,     // [64]
    const float* __restrict__ W2,     // [64][1]
    const float* __restrict__ b2,     // [1]
    float* __restrict__ ws)
{
    __shared__ float s_mp[ROWS * PITCH];   // m_part tile
    __shared__ float s_qp[NB * PITCH];     // q_part + b1
    __shared__ float s_qn[NB * PITCH];     // normalized query ctx
    __shared__ float s_out[NB * PITCH];    // output staging
    __shared__ float s_base[ROWS];         // 0.2 * freshness
    __shared__ float s_inv[ROWS];          // 0.3 / max(||mctx||, eps)

    const int tid = threadIdx.x;
    const int C0 = blockIdx.x * ROWS;

    // ---- stage 0: per-block recompute of qp/qn (all 32 b), mctx norms, base ----
    {
        const int b = tid >> 3, sl = tid & 7, j0 = sl * 8;
        const float* qrow = qc + b * 64;
        float acc[8];
        #pragma unroll
        for (int jj = 0; jj < 8; ++jj) acc[jj] = b1[j0 + jj];
        #pragma unroll 4
        for (int i = 0; i < 64; ++i) {
            float q = qrow[i];
            float4 wa = *(const float4*)&W1[i * 64 + j0];
            float4 wb = *(const float4*)&W1[i * 64 + j0 + 4];
            acc[0] = fmaf(q, wa.x, acc[0]); acc[1] = fmaf(q, wa.y, acc[1]);
            acc[2] = fmaf(q, wa.z, acc[2]); acc[3] = fmaf(q, wa.w, acc[3]);
            acc[4] = fmaf(q, wb.x, acc[4]); acc[5] = fmaf(q, wb.y, acc[5]);
            acc[6] = fmaf(q, wb.z, acc[6]); acc[7] = fmaf(q, wb.w, acc[7]);
        }
        #pragma unroll
        for (int jj = 0; jj < 8; ++jj) s_qp[b * PITCH + j0 + jj] = acc[jj];

        const float* xrow = qctx + b * 64;
        float ss = 0.f;
        #pragma unroll
        for (int i4 = 0; i4 < 16; ++i4) {
            float4 x = *(const float4*)&xrow[i4 * 4];
            ss = fmaf(x.x, x.x, ss); ss = fmaf(x.y, x.y, ss);
            ss = fmaf(x.z, x.z, ss); ss = fmaf(x.w, x.w, ss);
        }
        float rinv = 1.f / fmaxf(sqrtf(ss), CEPS);
        #pragma unroll
        for (int g = 0; g < 2; ++g) {
            float4 x = *(const float4*)&xrow[j0 + g * 4];
            s_qn[b * PITCH + j0 + g * 4 + 0] = x.x * rinv;
            s_qn[b * PITCH + j0 + g * 4 + 1] = x.y * rinv;
            s_qn[b * PITCH + j0 + g * 4 + 2] = x.z * rinv;
            s_qn[b * PITCH + j0 + g * 4 + 3] = x.w * rinv;
        }
    }
    if (tid < 64) {
        const float* xr = mctx + (size_t)(C0 + tid) * 64;
        float ss = 0.f;
        #pragma unroll
        for (int i4 = 0; i4 < 16; ++i4) {
            float4 x = *(const float4*)&xr[i4 * 4];
            ss = fmaf(x.x, x.x, ss); ss = fmaf(x.y, x.y, ss);
            ss = fmaf(x.z, x.z, ss); ss = fmaf(x.w, x.w, ss);
        }
        s_inv[tid]  = 0.3f / fmaxf(sqrtf(ss), CEPS);
        s_base[tid] = 0.2f * fresh[C0 + tid];
    }
    __syncthreads();

    // ---- phase A: m_part = MC[64x64] @ W1lo[64x64], register-tiled 4c x 4j,
    //      inputs straight from global/L1 (keeps the LDS pipe free) ----
    {
        const int c_lo = tid & 15;
        const int j0 = (tid >> 4) * 4;   // 0..60
        float acc[4][4] = {{0.f}};
        const float* mrow = mcont + (size_t)(C0 + c_lo) * 64;
        #pragma unroll 4
        for (int i4 = 0; i4 < 16; ++i4) {
            float4 w0 = *(const float4*)&W1[(64 + i4 * 4 + 0) * 64 + j0];
            float4 w1r = *(const float4*)&W1[(64 + i4 * 4 + 1) * 64 + j0];
            float4 w2r = *(const float4*)&W1[(64 + i4 * 4 + 2) * 64 + j0];
            float4 w3r = *(const float4*)&W1[(64 + i4 * 4 + 3) * 64 + j0];
            #pragma unroll
            for (int ci = 0; ci < 4; ++ci) {
                float4 m = *(const float4*)&mrow[ci * 1024 + i4 * 4];  // row c_lo+16ci
                acc[ci][0] = fmaf(m.x, w0.x, acc[ci][0]);
                acc[ci][1] = fmaf(m.x, w0.y, acc[ci][1]);
                acc[ci][2] = fmaf(m.x, w0.z, acc[ci][2]);
                acc[ci][3] = fmaf(m.x, w0.w, acc[ci][3]);
                acc[ci][0] = fmaf(m.y, w1r.x, acc[ci][0]);
                acc[ci][1] = fmaf(m.y, w1r.y, acc[ci][1]);
                acc[ci][2] = fmaf(m.y, w1r.z, acc[ci][2]);
                acc[ci][3] = fmaf(m.y, w1r.w, acc[ci][3]);
                acc[ci][0] = fmaf(m.z, w2r.x, acc[ci][0]);
                acc[ci][1] = fmaf(m.z, w2r.y, acc[ci][1]);
                acc[ci][2] = fmaf(m.z, w2r.z, acc[ci][2]);
                acc[ci][3] = fmaf(m.z, w2r.w, acc[ci][3]);
                acc[ci][0] = fmaf(m.w, w3r.x, acc[ci][0]);
                acc[ci][1] = fmaf(m.w, w3r.y, acc[ci][1]);
                acc[ci][2] = fmaf(m.w, w3r.z, acc[ci][2]);
                acc[ci][3] = fmaf(m.w, w3r.w, acc[ci][3]);
            }
        }
        #pragma unroll
        for (int ci = 0; ci < 4; ++ci)
            *(float4*)&s_mp[(c_lo + 16 * ci) * PITCH + j0] =
                make_float4(acc[ci][0], acc[ci][1], acc[ci][2], acc[ci][3]);
    }
    __syncthreads();

    // ---- phase B: 2 b x 4 c pairs/thread; mv from LDS, xv/w2 from global/L1 ----
    const int bq = (tid & 15) << 1;
    const int cq = (tid >> 4) << 2;
    float a1[2][4] = {{0.f}}, a2[2][4] = {{0.f}};
    const float* mxb = mctx + (size_t)C0 * 64;

    #pragma unroll 4
    for (int j4 = 0; j4 < 16; ++j4) {
        const int jo = j4 * 4;
        float4 w2v = *(const float4*)(W2 + jo);
        float4 qp0 = *(const float4*)&s_qp[ bq      * PITCH + jo];
        float4 qp1 = *(const float4*)&s_qp[(bq + 1) * PITCH + jo];
        float4 qn0 = *(const float4*)&s_qn[ bq      * PITCH + jo];
        float4 qn1 = *(const float4*)&s_qn[(bq + 1) * PITCH + jo];
        #pragma unroll
        for (int ci = 0; ci < 4; ++ci) {
            float4 mv = *(const float4*)&s_mp[(cq + ci) * PITCH + jo];
            float4 xv = *(const float4*)&mxb[(cq + ci) * 64 + jo];
            a1[0][ci] = fmaf(fmaxf(qp0.x + mv.x, 0.f), w2v.x, a1[0][ci]);
            a1[0][ci] = fmaf(fmaxf(qp0.y + mv.y, 0.f), w2v.y, a1[0][ci]);
            a1[0][ci] = fmaf(fmaxf(qp0.z + mv.z, 0.f), w2v.z, a1[0][ci]);
            a1[0][ci] = fmaf(fmaxf(qp0.w + mv.w, 0.f), w2v.w, a1[0][ci]);
            a2[0][ci] = fmaf(qn0.x, xv.x, a2[0][ci]);
            a2[0][ci] = fmaf(qn0.y, xv.y, a2[0][ci]);
            a2[0][ci] = fmaf(qn0.z, xv.z, a2[0][ci]);
            a2[0][ci] = fmaf(qn0.w, xv.w, a2[0][ci]);
            a1[1][ci] = fmaf(fmaxf(qp1.x + mv.x, 0.f), w2v.x, a1[1][ci]);
            a1[1][ci] = fmaf(fmaxf(qp1.y + mv.y, 0.f), w2v.y, a1[1][ci]);
            a1[1][ci] = fmaf(fmaxf(qp1.z + mv.z, 0.f), w2v.z, a1[1][ci]);
            a1[1][ci] = fmaf(fmaxf(qp1.w + mv.w, 0.f), w2v.w, a1[1][ci]);
            a2[1][ci] = fmaf(qn1.x, xv.x, a2[1][ci]);
            a2[1][ci] = fmaf(qn1.y, xv.y, a2[1][ci]);
            a2[1][ci] = fmaf(qn1.z, xv.z, a2[1][ci]);
            a2[1][ci] = fmaf(qn1.w, xv.w, a2[1][ci]);
        }
    }

    const float b2v = b2[0];
    #pragma unroll
    for (int bi = 0; bi < 2; ++bi)
        #pragma unroll
        for (int ci = 0; ci < 4; ++ci) {
            const int b = bq + bi, c = cq + ci;
            float logit = a1[bi][ci] + b2v;
            float sig = 0.5f / (1.f + expf(-logit));
            s_out[b * PITCH + c] = sig + a2[bi][ci] * s_inv[c] + s_base[c];
        }
    __syncthreads();

    #pragma unroll
    for (int it = 0; it < 2; ++it) {
        int idx = it * 256 + tid;        // 512 float4 = 32 b x 64 c
        int b = idx >> 4, c4 = idx & 15;
        *(float4*)&ws[WS_FINAL + (size_t)b * CAP + C0 + c4 * 4] =
            *(const float4*)&s_out[b * PITCH + c4 * 4];
    }
}

// ---- top-k phase 1: one wave per (row, 2048-chunk), register-resident ----
__global__ __launch_bounds__(64) void topk_part1(float* __restrict__ ws)
{
    const int lane = threadIdx.x;
    const int b = blockIdx.y;
    float* row = ws + WS_FINAL + (size_t)b * CAP;
    const int cbase = blockIdx.x * CHUNK;

    // v[4g+e] holds global index cbase + g*256 + lane*4 + e (dwordx4 loads)
    float v[32];
    #pragma unroll
    for (int g = 0; g < 8; ++g) {
        float4 t = *(const float4*)&row[cbase + g * 256 + lane * 4];
        v[4 * g + 0] = t.x; v[4 * g + 1] = t.y;
        v[4 * g + 2] = t.z; v[4 * g + 3] = t.w;
    }

    float outv = 0.f;
    int   outi = 0;

    for (int k = 0; k < TOPK; ++k) {
        float bv = v[0]; int bj = 0;
        #pragma unroll
        for (int j = 1; j < 32; ++j)
            if (v[j] > bv) { bv = v[j]; bj = j; }
        int bi = cbase + (bj >> 2) * 256 + lane * 4 + (bj & 3);
        // note: within a lane, ascending j = ascending global idx? j=4g+e ->
        // idx = g*256 + lane*4 + e: ascending j is ascending idx for fixed lane. ties -> lowest idx ok.

        #pragma unroll
        for (int off = 1; off < 64; off <<= 1) {
            float ov = __shfl_xor(bv, off, 64);
            int   oi = __shfl_xor(bi, off, 64);
            if (ov > bv || (ov == bv && oi < bi)) { bv = ov; bi = oi; }
        }
        if (lane == k) { outv = bv; outi = bi; }

        int rel = bi - cbase;
        bool mine = (((rel >> 2) & 63) == lane);
        int wj = ((rel >> 8) << 2) | (rel & 3);
        #pragma unroll
        for (int j = 0; j < 32; ++j)
            if (mine && wj == j) v[j] = -INFINITY;
    }

    if (lane < TOPK) {
        row[cbase + lane]        = outv;
        row[cbase + TOPK + lane] = __int_as_float(outi);
    }
}

// ---- top-k phase 2: one wave per row, merge 16x16 candidates + fused gather ----
__global__ __launch_bounds__(64) void topk_part2(
    const float* __restrict__ mcont,
    const float* __restrict__ fresh,
    const float* __restrict__ ws,
    float* __restrict__ out)
{
    const int lane = threadIdx.x;
    const int b = blockIdx.x;
    const float* row = ws + WS_FINAL + (size_t)b * CAP;

    float* out_content = out;                       // [32][16][64]
    float* out_sim     = out + NB * TOPK * 64;      // [32][16]
    float* out_tw      = out + NB * TOPK * 64 + NB * TOPK;

    const int chunk = lane & 15;
    const int s0 = lane >> 4;
    float v[4]; int iv[4];
    #pragma unroll
    for (int s = 0; s < 4; ++s) {
        v[s]  = row[chunk * CHUNK + s0 + 4 * s];
        iv[s] = __float_as_int(row[chunk * CHUNK + TOPK + s0 + 4 * s]);
    }

    float wval = 0.f; int widx = 0;
    for (int k = 0; k < TOPK; ++k) {
        float bv = v[0]; int bi = iv[0];
        #pragma unroll
        for (int s = 1; s < 4; ++s)
            if (v[s] > bv || (v[s] == bv && iv[s] < bi)) { bv = v[s]; bi = iv[s]; }
        #pragma unroll
        for (int off = 1; off < 64; off <<= 1) {
            float ov = __shfl_xor(bv, off, 64);
            int   oi = __shfl_xor(bi, off, 64);
            if (ov > bv || (ov == bv && oi < bi)) { bv = ov; bi = oi; }
        }
        if (lane == k) { wval = bv; widx = bi; }
        #pragma unroll
        for (int s = 0; s < 4; ++s)
            if (iv[s] == bi) v[s] = -INFINITY;
    }

    if (lane < TOPK) {
        out_sim[b * TOPK + lane] = wval;
        out_tw [b * TOPK + lane] = fresh[widx];
    }

    #pragma unroll
    for (int r = 0; r < TOPK; ++r) {
        int wi = __shfl(widx, r, 64);
        out_content[(size_t)b * TOPK * 64 + r * 64 + lane] =
            mcont[(size_t)wi * 64 + lane];
    }
}

extern "C" void kernel_launch(void* const* d_in, const int* in_sizes, int n_in,
                              void* d_out, int out_size, void* d_ws, size_t ws_size,
                              hipStream_t stream) {
    const float* qc    = (const float*)d_in[0];
    const float* qctx  = (const float*)d_in[1];
    const float* mcont = (const float*)d_in[2];
    const float* mctx  = (const float*)d_in[3];
    const float* fresh = (const float*)d_in[4];
    const float* W1    = (const float*)d_in[5];
    const float* b1    = (const float*)d_in[6];
    const float* W2    = (const float*)d_in[7];
    const float* b2    = (const float*)d_in[8];
    float* out = (float*)d_out;
    float* ws  = (float*)d_ws;

    score_kernel<<<NBLK, 256, 0, stream>>>(qc, qctx, mcont, mctx, fresh,
                                           W1, b1, W2, b2, ws);
    topk_part1<<<dim3(NCHUNK, NB), 64, 0, stream>>>(ws);
    topk_part2<<<NB, 64, 0, stream>>>(mcont, fresh, ws, out);
}

// Round 5
// 137.421 us; speedup vs baseline: 1.1161x; 1.1161x over previous
//
#include <hip/hip_runtime.h>
#include <math.h>

#define CAP   32768
#define NB    32
#define ROWS  64
#define NBLK  (CAP / ROWS)   // 512
#define TOPK  16
#define CEPS  1e-8f

#define PITCH 68              // LDS row pitch (floats); 16B-aligned rows
#define CHUNK 2048
#define NCHUNK (CAP / CHUNK)  // 16

// ws layout (floats)
#define WS_QP    0            // [32][64] q_part + b1
#define WS_QN    2048         // [32][64] normalized query context
#define WS_FINAL 4096         // [32][32768] final scores

__global__ __launch_bounds__(64) void prep_kernel(
    const float* __restrict__ qc,    // [32][64]
    const float* __restrict__ qctx,  // [32][64]
    const float* __restrict__ W1,    // [128][64]
    const float* __restrict__ b1,    // [64]
    float* __restrict__ ws)
{
    const int b = blockIdx.x;
    const int j = threadIdx.x;

    float a0 = b1[j], a1 = 0.f, a2 = 0.f, a3 = 0.f;
    #pragma unroll
    for (int i = 0; i < 64; i += 4) {
        a0 = fmaf(qc[b * 64 + i + 0], W1[(i + 0) * 64 + j], a0);
        a1 = fmaf(qc[b * 64 + i + 1], W1[(i + 1) * 64 + j], a1);
        a2 = fmaf(qc[b * 64 + i + 2], W1[(i + 2) * 64 + j], a2);
        a3 = fmaf(qc[b * 64 + i + 3], W1[(i + 3) * 64 + j], a3);
    }
    ws[WS_QP + b * 64 + j] = (a0 + a1) + (a2 + a3);

    float x = qctx[b * 64 + j];
    float ss = x * x;
    ss += __shfl_xor(ss, 1,  64);
    ss += __shfl_xor(ss, 2,  64);
    ss += __shfl_xor(ss, 4,  64);
    ss += __shfl_xor(ss, 8,  64);
    ss += __shfl_xor(ss, 16, 64);
    ss += __shfl_xor(ss, 32, 64);
    ws[WS_QN + b * 64 + j] = x / fmaxf(sqrtf(ss), CEPS);
}

__global__ __launch_bounds__(256) void score_kernel(
    const float* __restrict__ mcont,  // [CAP][64]
    const float* __restrict__ mctx,   // [CAP][64]
    const float* __restrict__ fresh,  // [CAP]
    const float* __restrict__ W1,     // [128][64]
    const float* __restrict__ W2,     // [64]
    const float* __restrict__ b2,     // [1]
    float* __restrict__ ws)
{
    __shared__ float s_mc[ROWS * PITCH];   // mc tile; after phase A: m_part^T [j][c]
    __shared__ float s_qp[NB * PITCH];
    __shared__ float s_qn[NB * PITCH];
    __shared__ float s_base[ROWS];         // 0.2 * freshness
    __shared__ float s_inv[ROWS];          // 0.3 / max(||mctx||, eps)

    const int tid = threadIdx.x;
    const int C0 = blockIdx.x * ROWS;

    // ---- staging: mc tile (coalesced), qp/qn, mctx norms ----
    const float4* g_mc = (const float4*)(mcont + (size_t)C0 * 64);
    #pragma unroll
    for (int t = tid; t < ROWS * 16; t += 256) {
        int r = t >> 4, c4 = t & 15;
        *(float4*)&s_mc[r * PITCH + c4 * 4] = g_mc[t];
    }
    const float4* g_qp = (const float4*)(ws + WS_QP);
    const float4* g_qn = (const float4*)(ws + WS_QN);
    #pragma unroll
    for (int t = tid; t < NB * 16; t += 256) {
        int r = t >> 4, c4 = t & 15;
        *(float4*)&s_qp[r * PITCH + c4 * 4] = g_qp[t];
        *(float4*)&s_qn[r * PITCH + c4 * 4] = g_qn[t];
    }
    {   // mctx norms: thread t -> row r=t>>2, quarter q=t&3 (coalesced b128 loads)
        const int r = tid >> 2, q = tid & 3;
        const float* xr = mctx + (size_t)(C0 + r) * 64 + q * 16;
        float ss = 0.f;
        #pragma unroll
        for (int i = 0; i < 4; ++i) {
            float4 x = *(const float4*)&xr[i * 4];
            ss = fmaf(x.x, x.x, ss); ss = fmaf(x.y, x.y, ss);
            ss = fmaf(x.z, x.z, ss); ss = fmaf(x.w, x.w, ss);
        }
        ss += __shfl_xor(ss, 1, 64);
        ss += __shfl_xor(ss, 2, 64);
        if (q == 0) {
            s_inv[r]  = 0.3f / fmaxf(sqrtf(ss), CEPS);
            s_base[r] = 0.2f * fresh[C0 + r];
        }
    }
    __syncthreads();

    // ---- phase A: m_part = MC @ W1lo, 4c x 4j register tile.
    //      mc rows from LDS (stride 68 -> 2-way, free); W1 from global (broadcast, L1-hot)
    const int c_lo = tid & 15;
    const int j0 = (tid >> 4) * 4;
    {
        float acc[4][4] = {{0.f}};
        #pragma unroll 4
        for (int i4 = 0; i4 < 16; ++i4) {
            float4 w0 = *(const float4*)&W1[(64 + i4 * 4 + 0) * 64 + j0];
            float4 w1r = *(const float4*)&W1[(64 + i4 * 4 + 1) * 64 + j0];
            float4 w2r = *(const float4*)&W1[(64 + i4 * 4 + 2) * 64 + j0];
            float4 w3r = *(const float4*)&W1[(64 + i4 * 4 + 3) * 64 + j0];
            #pragma unroll
            for (int ci = 0; ci < 4; ++ci) {
                float4 m = *(const float4*)&s_mc[(c_lo + 16 * ci) * PITCH + i4 * 4];
                acc[ci][0] = fmaf(m.x, w0.x, acc[ci][0]);
                acc[ci][1] = fmaf(m.x, w0.y, acc[ci][1]);
                acc[ci][2] = fmaf(m.x, w0.z, acc[ci][2]);
                acc[ci][3] = fmaf(m.x, w0.w, acc[ci][3]);
                acc[ci][0] = fmaf(m.y, w1r.x, acc[ci][0]);
                acc[ci][1] = fmaf(m.y, w1r.y, acc[ci][1]);
                acc[ci][2] = fmaf(m.y, w1r.z, acc[ci][2]);
                acc[ci][3] = fmaf(m.y, w1r.w, acc[ci][3]);
                acc[ci][0] = fmaf(m.z, w2r.x, acc[ci][0]);
                acc[ci][1] = fmaf(m.z, w2r.y, acc[ci][1]);
                acc[ci][2] = fmaf(m.z, w2r.z, acc[ci][2]);
                acc[ci][3] = fmaf(m.z, w2r.w, acc[ci][3]);
                acc[ci][0] = fmaf(m.w, w3r.x, acc[ci][0]);
                acc[ci][1] = fmaf(m.w, w3r.y, acc[ci][1]);
                acc[ci][2] = fmaf(m.w, w3r.z, acc[ci][2]);
                acc[ci][3] = fmaf(m.w, w3r.w, acc[ci][3]);
            }
        }
        __syncthreads();   // all s_mc reads done; now overlay with m_part^T
        #pragma unroll
        for (int jj = 0; jj < 4; ++jj)
            #pragma unroll
            for (int ci = 0; ci < 4; ++ci)
                s_mc[(j0 + jj) * PITCH + c_lo + 16 * ci] = acc[ci][jj];  // 2-way, free
    }
    __syncthreads();

    // ---- phase B: 2b x 4c per thread; a1 c-vectorized via m_part^T float4 ----
    const int bq = (tid & 15) << 1;
    const int cq = (tid >> 4) << 2;
    float4 a1v[2];
    a1v[0] = make_float4(0.f, 0.f, 0.f, 0.f);
    a1v[1] = make_float4(0.f, 0.f, 0.f, 0.f);
    float a2[2][4] = {{0.f}};
    const float* mxb = mctx + (size_t)C0 * 64;

    #pragma unroll 4
    for (int j4 = 0; j4 < 16; ++j4) {
        const int jo = j4 * 4;
        float4 w2v = *(const float4*)(W2 + jo);                       // uniform -> s_load
        float4 qp0 = *(const float4*)&s_qp[ bq      * PITCH + jo];
        float4 qp1 = *(const float4*)&s_qp[(bq + 1) * PITCH + jo];
        float4 qn0 = *(const float4*)&s_qn[ bq      * PITCH + jo];
        float4 qn1 = *(const float4*)&s_qn[(bq + 1) * PITCH + jo];
        float4 m0 = *(const float4*)&s_mc[(jo + 0) * PITCH + cq];     // float4 over c
        float4 m1 = *(const float4*)&s_mc[(jo + 1) * PITCH + cq];
        float4 m2 = *(const float4*)&s_mc[(jo + 2) * PITCH + cq];
        float4 m3 = *(const float4*)&s_mc[(jo + 3) * PITCH + cq];

        #pragma unroll
        for (int bi = 0; bi < 2; ++bi) {
            float4 qp = bi ? qp1 : qp0;
            float4& av = a1v[bi];
            av.x = fmaf(fmaxf(qp.x + m0.x, 0.f), w2v.x, av.x);
            av.y = fmaf(fmaxf(qp.x + m0.y, 0.f), w2v.x, av.y);
            av.z = fmaf(fmaxf(qp.x + m0.z, 0.f), w2v.x, av.z);
            av.w = fmaf(fmaxf(qp.x + m0.w, 0.f), w2v.x, av.w);
            av.x = fmaf(fmaxf(qp.y + m1.x, 0.f), w2v.y, av.x);
            av.y = fmaf(fmaxf(qp.y + m1.y, 0.f), w2v.y, av.y);
            av.z = fmaf(fmaxf(qp.y + m1.z, 0.f), w2v.y, av.z);
            av.w = fmaf(fmaxf(qp.y + m1.w, 0.f), w2v.y, av.w);
            av.x = fmaf(fmaxf(qp.z + m2.x, 0.f), w2v.z, av.x);
            av.y = fmaf(fmaxf(qp.z + m2.y, 0.f), w2v.z, av.y);
            av.z = fmaf(fmaxf(qp.z + m2.z, 0.f), w2v.z, av.z);
            av.w = fmaf(fmaxf(qp.z + m2.w, 0.f), w2v.z, av.w);
            av.x = fmaf(fmaxf(qp.w + m3.x, 0.f), w2v.w, av.x);
            av.y = fmaf(fmaxf(qp.w + m3.y, 0.f), w2v.w, av.y);
            av.z = fmaf(fmaxf(qp.w + m3.z, 0.f), w2v.w, av.z);
            av.w = fmaf(fmaxf(qp.w + m3.w, 0.f), w2v.w, av.w);
        }
        #pragma unroll
        for (int ci = 0; ci < 4; ++ci) {
            float4 xv = *(const float4*)&mxb[(cq + ci) * 64 + jo];    // L1-hot
            a2[0][ci] = fmaf(qn0.x, xv.x, a2[0][ci]);
            a2[0][ci] = fmaf(qn0.y, xv.y, a2[0][ci]);
            a2[0][ci] = fmaf(qn0.z, xv.z, a2[0][ci]);
            a2[0][ci] = fmaf(qn0.w, xv.w, a2[0][ci]);
            a2[1][ci] = fmaf(qn1.x, xv.x, a2[1][ci]);
            a2[1][ci] = fmaf(qn1.y, xv.y, a2[1][ci]);
            a2[1][ci] = fmaf(qn1.z, xv.z, a2[1][ci]);
            a2[1][ci] = fmaf(qn1.w, xv.w, a2[1][ci]);
        }
    }

    // ---- epilogue: dense float4 stores, 2 per thread ----
    const float b2v = b2[0];
    float4 inv4  = *(const float4*)&s_inv[cq];
    float4 base4 = *(const float4*)&s_base[cq];
    #pragma unroll
    for (int bi = 0; bi < 2; ++bi) {
        float4 r;
        r.x = 0.5f / (1.f + expf(-(a1v[bi].x + b2v))) + a2[bi][0] * inv4.x + base4.x;
        r.y = 0.5f / (1.f + expf(-(a1v[bi].y + b2v))) + a2[bi][1] * inv4.y + base4.y;
        r.z = 0.5f / (1.f + expf(-(a1v[bi].z + b2v))) + a2[bi][2] * inv4.z + base4.z;
        r.w = 0.5f / (1.f + expf(-(a1v[bi].w + b2v))) + a2[bi][3] * inv4.w + base4.w;
        *(float4*)&ws[WS_FINAL + (size_t)(bq + bi) * CAP + C0 + cq] = r;
    }
}

// ---- top-k phase 1: one wave per (row, 2048-chunk), register-resident ----
__global__ __launch_bounds__(64) void topk_part1(float* __restrict__ ws)
{
    const int lane = threadIdx.x;
    const int b = blockIdx.y;
    float* row = ws + WS_FINAL + (size_t)b * CAP;
    const int cbase = blockIdx.x * CHUNK;

    float v[32];
    #pragma unroll
    for (int g = 0; g < 8; ++g) {
        float4 t = *(const float4*)&row[cbase + g * 256 + lane * 4];
        v[4 * g + 0] = t.x; v[4 * g + 1] = t.y;
        v[4 * g + 2] = t.z; v[4 * g + 3] = t.w;
    }

    float outv = 0.f;
    int   outi = 0;

    for (int k = 0; k < TOPK; ++k) {
        float bv = v[0]; int bj = 0;
        #pragma unroll
        for (int j = 1; j < 32; ++j)
            if (v[j] > bv) { bv = v[j]; bj = j; }
        int bi = cbase + (bj >> 2) * 256 + lane * 4 + (bj & 3);

        #pragma unroll
        for (int off = 1; off < 64; off <<= 1) {
            float ov = __shfl_xor(bv, off, 64);
            int   oi = __shfl_xor(bi, off, 64);
            if (ov > bv || (ov == bv && oi < bi)) { bv = ov; bi = oi; }
        }
        if (lane == k) { outv = bv; outi = bi; }

        int rel = bi - cbase;
        bool mine = (((rel >> 2) & 63) == lane);
        int wj = ((rel >> 8) << 2) | (rel & 3);
        #pragma unroll
        for (int j = 0; j < 32; ++j)
            if (mine && wj == j) v[j] = -INFINITY;
    }

    if (lane < TOPK) {
        row[cbase + lane]        = outv;
        row[cbase + TOPK + lane] = __int_as_float(outi);
    }
}

// ---- top-k phase 2: one wave per row, merge 16x16 candidates + fused gather ----
__global__ __launch_bounds__(64) void topk_part2(
    const float* __restrict__ mcont,
    const float* __restrict__ fresh,
    const float* __restrict__ ws,
    float* __restrict__ out)
{
    const int lane = threadIdx.x;
    const int b = blockIdx.x;
    const float* row = ws + WS_FINAL + (size_t)b * CAP;

    float* out_content = out;                       // [32][16][64]
    float* out_sim     = out + NB * TOPK * 64;      // [32][16]
    float* out_tw      = out + NB * TOPK * 64 + NB * TOPK;

    const int chunk = lane & 15;
    const int s0 = lane >> 4;
    float v[4]; int iv[4];
    #pragma unroll
    for (int s = 0; s < 4; ++s) {
        v[s]  = row[chunk * CHUNK + s0 + 4 * s];
        iv[s] = __float_as_int(row[chunk * CHUNK + TOPK + s0 + 4 * s]);
    }

    float wval = 0.f; int widx = 0;
    for (int k = 0; k < TOPK; ++k) {
        float bv = v[0]; int bi = iv[0];
        #pragma unroll
        for (int s = 1; s < 4; ++s)
            if (v[s] > bv || (v[s] == bv && iv[s] < bi)) { bv = v[s]; bi = iv[s]; }
        #pragma unroll
        for (int off = 1; off < 64; off <<= 1) {
            float ov = __shfl_xor(bv, off, 64);
            int   oi = __shfl_xor(bi, off, 64);
            if (ov > bv || (ov == bv && oi < bi)) { bv = ov; bi = oi; }
        }
        if (lane == k) { wval = bv; widx = bi; }
        #pragma unroll
        for (int s = 0; s < 4; ++s)
            if (iv[s] == bi) v[s] = -INFINITY;
    }

    if (lane < TOPK) {
        out_sim[b * TOPK + lane] = wval;
        out_tw [b * TOPK + lane] = fresh[widx];
    }

    #pragma unroll
    for (int r = 0; r < TOPK; ++r) {
        int wi = __shfl(widx, r, 64);
        out_content[(size_t)b * TOPK * 64 + r * 64 + lane] =
            mcont[(size_t)wi * 64 + lane];
    }
}

extern "C" void kernel_launch(void* const* d_in, const int* in_sizes, int n_in,
                              void* d_out, int out_size, void* d_ws, size_t ws_size,
                              hipStream_t stream) {
    const float* qc    = (const float*)d_in[0];
    const float* qctx  = (const float*)d_in[1];
    const float* mcont = (const float*)d_in[2];
    const float* mctx  = (const float*)d_in[3];
    const float* fresh = (const float*)d_in[4];
    const float* W1    = (const float*)d_in[5];
    const float* b1    = (const float*)d_in[6];
    const float* W2    = (const float*)d_in[7];
    const float* b2    = (const float*)d_in[8];
    float* out = (float*)d_out;
    float* ws  = (float*)d_ws;

    prep_kernel<<<NB, 64, 0, stream>>>(qc, qctx, W1, b1, ws);
    score_kernel<<<NBLK, 256, 0, stream>>>(mcont, mctx, fresh, W1, W2, b2, ws);
    topk_part1<<<dim3(NCHUNK, NB), 64, 0, stream>>>(ws);
    topk_part2<<<NB, 64, 0, stream>>>(mcont, fresh, ws, out);
}